// Round 10
// baseline (164.906 us; speedup 1.0000x reference)
//
#include <hip/hip_runtime.h>
#include <cstdint>
#include <cstddef>

#define B_  8
#define T_  1024
#define C_  768
#define H_  12
#define HD_ 64
#define K3_ 2304   // 3*C

typedef unsigned short u16;
typedef __attribute__((ext_vector_type(8))) short bf16x8;   // 8 bf16 (4 VGPRs)
typedef __attribute__((ext_vector_type(4))) float f32x4;    // 4 fp32 acc

#define MFMA __builtin_amdgcn_mfma_f32_16x16x32_bf16

__device__ __forceinline__ u16 f2bf(float f) {
    unsigned u = __builtin_bit_cast(unsigned, f);
    u += 0x7fffu + ((u >> 16) & 1u);           // round-to-nearest-even
    return (u16)(u >> 16);
}

// pack two fp32 -> bf16x2 dword (round-half-up; P>=0, feeds bf16 MFMA)
__device__ __forceinline__ unsigned pk2bf(float a, float b) {
    unsigned ua = __builtin_bit_cast(unsigned, a) + 0x8000u;
    unsigned ub = __builtin_bit_cast(unsigned, b) + 0x8000u;
    return (ua >> 16) | (ub & 0xffff0000u);
}

// async global->LDS, 16 B per lane. LDS dest = wave-uniform base + lane*16.
#define GLL16(gp, lp) __builtin_amdgcn_global_load_lds( \
    (__attribute__((address_space(1))) unsigned int*)(gp), \
    (__attribute__((address_space(3))) unsigned int*)(lp), 16, 0, 0)

// ---------------- prep: x->bf16 + both weight transposes, one kernel ----------------
__device__ __forceinline__ void tcvt_tile(const float* __restrict__ in, u16* __restrict__ out,
                                          int R, int Cc, int bx, int by, int tid, float* tile /*32x33*/) {
    int bc = bx * 32, br = by * 32;
    int tx = tid & 31, ty = tid >> 5;   // (32, 8)
    #pragma unroll
    for (int kk = 0; kk < 32; kk += 8)
        tile[(ty + kk) * 33 + tx] = in[(size_t)(br + ty + kk) * Cc + bc + tx];
    __syncthreads();
    #pragma unroll
    for (int kk = 0; kk < 32; kk += 8)
        out[(size_t)(bc + ty + kk) * R + br + tx] = f2bf(tile[tx * 33 + ty + kk]);
}

__global__ void prep(const float* __restrict__ x, u16* __restrict__ xb,
                     const float* __restrict__ wa, u16* __restrict__ wat,
                     const float* __restrict__ wp, u16* __restrict__ wpt) {
    __shared__ float tile[32 * 33];
    int bid = blockIdx.x, tid = threadIdx.x;
    if (bid < 6144) {                      // cvt: 8192*768/4 elements of float4
        int i = bid * 256 + tid;
        float4 v = ((const float4*)x)[i];
        ushort4 o;
        o.x = f2bf(v.x); o.y = f2bf(v.y); o.z = f2bf(v.z); o.w = f2bf(v.w);
        ((ushort4*)xb)[i] = o;
    } else if (bid < 6144 + 1728) {        // w_attn [768][2304] -> [2304][768]
        int b = bid - 6144;
        tcvt_tile(wa, wat, C_, K3_, b % 72, b / 72, tid, tile);
    } else {                               // w_proj [768][768] -> [768][768]^T
        int b = bid - 7872;
        tcvt_tile(wp, wpt, C_, C_, b % 24, b / 24, tid, tile);
    }
}

// ============ 4-waves/SIMD pipelined GEMM core ============
// BM=128, BN=96, BK=64, 512 threads (8 waves, 4M x 2N), per-wave 32x48 (2x3 frags).
// LDS: 2-slot ring (A 2x16KB + B 2x12KB = 56KB) -> 2 blocks/CU x 8 waves
// = 16 waves/CU = 4 waves/SIMD (all prior configs were 2/SIMD at MfmaUtil 22%).
// Staging per tile: A = 2 uniform wave-issues (64 rows each); B = 1 uniform
// (rows 0-63) + 1 on tid<256 (rows 64-95, wave-aligned). Waves carry 4 or 3
// loads/tile; uniform vmcnt(3) = exact drain for 3-load waves, safe 1-load
// over-drain for 4-load waves; NEVER 0 in steady state. Tail: vmcnt(0).
// Phase kt: {10 ds_read slot p=kt&1, 12 MFMA, BAR, stage kt+2 -> slot p
// (WAR-safe), vmcnt(3), BAR}. Swizzle: 128B rows, 3-bit XOR chunk^(row&7)
// both sides (round-0-verified conflict-free).
#define VMW3 asm volatile("s_waitcnt vmcnt(3)" ::: "memory")
#define VMW0 asm volatile("s_waitcnt vmcnt(0)" ::: "memory")
#define BAR  __builtin_amdgcn_s_barrier()

__device__ __forceinline__ void gemm_pipe(const u16* __restrict__ A, const u16* __restrict__ Bt,
                                          int m0, int n0, u16* SM, f32x4 (&acc)[2][3]) {
    const int K = C_;
    int tid = threadIdx.x;
    int lane = tid & 63, wv = tid >> 6;
    int wr = wv >> 1, wc = wv & 1;          // wave grid 4M x 2N
    int r16 = lane & 15, quad = lane >> 4;
    int sw = r16 & 7;
    int x0 = (quad ^ sw) * 8;               // kk=0 swizzled 16B chunk (u16 units)
    int x1 = ((4 + quad) ^ sw) * 8;         // kk=1
    int arow = (wr * 32 + r16) * 64;
    int brow = (wc * 48 + r16) * 64;
    // staging: thread t -> row t>>3 (0..63), chunk (t&7)^(row&7); LDS linear t*16B
    int tr = tid >> 3;
    int tb = (tid & 7) ^ (tr & 7);
    const u16* Ag = A  + (size_t)(m0 + tr) * K + tb * 8;
    const u16* Bg = Bt + (size_t)(n0 + tr) * K + tb * 8;
    u16* SLa = SM + tid * 8;                // A call covers 8KB (64 rows) per issue
    u16* SLb = SM + 16384 + tid * 8;
    const u16* SMB = SM + 16384;

#define STG_T(ss, kO) { \
    GLL16(Ag + (kO),                       SLa + (ss) * 8192); \
    GLL16(Ag + (size_t)64 * K + (kO),      SLa + (ss) * 8192 + 4096); \
    GLL16(Bg + (kO),                       SLb + (ss) * 6144); \
    if (tid < 256) GLL16(Bg + (size_t)64 * K + (kO), SLb + (ss) * 6144 + 4096); }
#define RDH(rs, XC, af, bf) { \
    const u16* Ar_ = SM  + (rs) * 8192 + arow; \
    const u16* Br_ = SMB + (rs) * 6144 + brow; \
    _Pragma("unroll") for (int i_ = 0; i_ < 2; i_++) af[i_] = *(const bf16x8*)&Ar_[i_ * 1024 + (XC)]; \
    _Pragma("unroll") for (int j_ = 0; j_ < 3; j_++) bf[j_] = *(const bf16x8*)&Br_[j_ * 1024 + (XC)]; }
#define MMH(af, bf) { \
    __builtin_amdgcn_s_setprio(1); \
    _Pragma("unroll") for (int i_ = 0; i_ < 2; i_++) \
    _Pragma("unroll") for (int j_ = 0; j_ < 3; j_++) \
        acc[i_][j_] = MFMA(af[i_], bf[j_], acc[i_][j_], 0, 0, 0); \
    __builtin_amdgcn_s_setprio(0); }

    // prologue: tile0 -> slot0, tile1 -> slot1; drain tile0 (vmcnt(3) exact/safe)
    STG_T(0, 0); STG_T(1, 64);
    VMW3; BAR;

    #pragma unroll
    for (int kt = 0; kt < 10; ++kt) {        // tiles 0..9; stages tiles 2..11
        int p = kt & 1;
        bf16x8 a0[2], b0[3], a1[2], b1[3];
        RDH(p, x0, a0, b0); RDH(p, x1, a1, b1);
        MMH(a0, b0); MMH(a1, b1);
        BAR;                                 // all waves' reads of slot p done
        STG_T(p, (kt + 2) * 64);             // overwrite slot p with tile kt+2
        VMW3;                                // tile kt+1 fully landed
        BAR;
    }
    {                                        // kt=10 (slot 0, tile 10)
        bf16x8 a0[2], b0[3], a1[2], b1[3];
        RDH(0, x0, a0, b0); RDH(0, x1, a1, b1);
        MMH(a0, b0); MMH(a1, b1);
        VMW0; BAR;                           // tile 11 fully landed
    }
    {                                        // kt=11 (slot 1, tile 11)
        bf16x8 a0[2], b0[3], a1[2], b1[3];
        RDH(1, x0, a0, b0); RDH(1, x1, a1, b1);
        MMH(a0, b0); MMH(a1, b1);
    }
#undef STG_T
#undef RDH
#undef MMH
}

// ---------------- GEMM1: qkv = x @ w_attn + b_attn, scatter to q/k/v ----------------
// 1536 blocks = 3 exact 2-blocks/CU rounds; 24 n-panels of 96 cols.
__launch_bounds__(512, 4)
__global__ void gemm_qkv(const u16* __restrict__ A, const u16* __restrict__ Bt,
                         const float* __restrict__ bias,
                         u16* __restrict__ q, u16* __restrict__ k, u16* __restrict__ v) {
    __shared__ __align__(16) u16 SM[28672];      // 56KB ring; Cs overlays in epilogue
    int id = blockIdx.x;                          // 1536 = 8 xcd * (8 m x 24 n)
    int xcd = id & 7, j = id >> 3;
    int m0 = (xcd * 8 + (j & 7)) * 128;           // XCD owns contiguous 8-tile A slab
    int np = j >> 3;                              // n-panel 0..23 (96 cols each)
    f32x4 acc[2][3] = {};
    gemm_pipe(A, Bt, m0, np * 96, SM, acc);

    int tid = threadIdx.x;
    int lane = tid & 63, wv = tid >> 6;
    int wr = wv >> 1, wc = wv & 1;
    int r16 = lane & 15, quad = lane >> 4;
    __syncthreads();                              // ring reads drained before Cs overlay

    int sec = np >> 3;                 // block-uniform: 0=q, 1=k, 2=v (8 panels each)
    int cc0 = (np & 7) * 96;           // col offset within section
    int b = m0 >> 10, t0 = m0 & 1023;

    if (sec == 2) {
        #pragma unroll
        for (int i = 0; i < 2; i++) {
            #pragma unroll
            for (int jj = 0; jj < 3; jj++) {
                int cc = cc0 + wc * 48 + jj * 16 + r16;
                float bv = bias[2 * C_ + cc];
                int h = cc >> 6, hd = cc & 63;
                int t = t0 + wr * 32 + i * 16 + quad * 4;
                ushort4 ov;
                ov.x = f2bf(acc[i][jj][0] + bv); ov.y = f2bf(acc[i][jj][1] + bv);
                ov.z = f2bf(acc[i][jj][2] + bv); ov.w = f2bf(acc[i][jj][3] + bv);
                *(ushort4*)(v + (((size_t)b * H_ + h) * HD_ + hd) * T_ + t) = ov;
            }
        }
    } else {
        float scale = (sec == 0) ? 0.125f : 1.0f;
        u16* dst = (sec == 0) ? q : k;
        u16 (*Cs)[104] = (u16(*)[104])SM;          // 128x104 (208B rows, 16B-aligned)
        #pragma unroll
        for (int i = 0; i < 2; i++)
            #pragma unroll
            for (int jj = 0; jj < 3; jj++) {
                int col = wc * 48 + jj * 16 + r16;
                float bv = bias[sec * C_ + cc0 + col];
                #pragma unroll
                for (int r = 0; r < 4; r++)
                    Cs[wr * 32 + i * 16 + quad * 4 + r][col] = f2bf((acc[i][jj][r] + bv) * scale);
            }
        __syncthreads();
        if (tid < 384) {                           // 32 rows x 12 chunks per pass
            int ch = tid % 12;                     // 16B chunk within 96 cols
            int rsel = tid / 12;                   // 0..31
            int cc = cc0 + ch * 8;
            int h = cc >> 6, hd = cc & 63;         // 8-col chunk never crosses a head
            u16* dbase = dst + ((size_t)b * H_ + h) * T_ * HD_ + hd;
            #pragma unroll
            for (int p = 0; p < 4; p++) {
                int rl = p * 32 + rsel;
                *(uint4*)(dbase + (size_t)(t0 + rl) * HD_) = *(const uint4*)&Cs[rl][ch * 8];
            }
        }
    }
}

// ---------------- GEMM2: out = y @ w_proj + b_proj (fp32 out) ----------------
__launch_bounds__(512, 4)
__global__ void gemm_proj(const u16* __restrict__ A, const u16* __restrict__ Bt,
                          const float* __restrict__ bias, float* __restrict__ out) {
    __shared__ __align__(16) u16 SM[28672];
    int id = blockIdx.x;                          // 512 = 8 xcd * (8 m x 8 n) -> 1 full round
    int xcd = id & 7, j = id >> 3;
    int m0 = (xcd * 8 + (j & 7)) * 128;
    int n0 = (j >> 3) * 96;
    f32x4 acc[2][3] = {};
    gemm_pipe(A, Bt, m0, n0, SM, acc);

    int tid = threadIdx.x;
    int lane = tid & 63, wv = tid >> 6;
    int wr = wv >> 1, wc = wv & 1;
    int r16 = lane & 15, quad = lane >> 4;
    #pragma unroll
    for (int i = 0; i < 2; i++) {
        #pragma unroll
        for (int jj = 0; jj < 3; jj++) {
            int gn = n0 + wc * 48 + jj * 16 + r16;
            float bv = bias[gn];
            #pragma unroll
            for (int r = 0; r < 4; r++) {
                int gm = m0 + wr * 32 + i * 16 + quad * 4 + r;
                out[(size_t)gm * C_ + gn] = acc[i][jj][r] + bv;
            }
        }
    }
}

// ---------------- Flash attention: LDS-staged K/V (double-buffered), paired q-tiles ----
__launch_bounds__(256, 2)
__global__ void attn(const u16* __restrict__ q, const u16* __restrict__ k,
                     const u16* __restrict__ v, u16* __restrict__ y) {
    __shared__ __align__(16) u16 Kb[2][64][64];     // [buf][key][hd]
    __shared__ __align__(16) u16 Vb[2][64][64];     // [buf][hd][key]
    __shared__ __align__(16) u16 P[4][2][16][72];   // per-wave, per-tile P^T
    int tid = threadIdx.x, lane = tid & 63, w = tid >> 6;
    int r16 = lane & 15, quad = lane >> 4;
    int id = blockIdx.x;
    int bh = id % 96;             // same head -> ids 96 apart -> same XCD (96%8==0)
    int bi = id / 96;             // 0..7; bi=0 (longest, n64=16) dispatched first
    int b = bh / H_, h = bh - b * H_;
    int x = bi * 4 + w;           // 0..31
    int t_lo = x, t_hi = 63 - x;
    int qb_lo = t_lo * 16, qb_hi = t_hi * 16;
    const u16* qh = q + (size_t)bh * T_ * HD_;
    const u16* kh = k + (size_t)bh * T_ * HD_;
    const u16* vh = v + (size_t)bh * HD_ * T_;   // [HD][T]

    bf16x8 ql0 = *(const bf16x8*)(qh + (size_t)(qb_lo + r16) * HD_ + quad * 8);
    bf16x8 ql1 = *(const bf16x8*)(qh + (size_t)(qb_lo + r16) * HD_ + 32 + quad * 8);
    bf16x8 qh0 = *(const bf16x8*)(qh + (size_t)(qb_hi + r16) * HD_ + quad * 8);
    bf16x8 qh1 = *(const bf16x8*)(qh + (size_t)(qb_hi + r16) * HD_ + 32 + quad * 8);

    f32x4 oL[4] = {}, oH[4] = {};
    float lL = 0.f, lH = 0.f;
    int qyL = qb_lo + r16, qyH = qb_hi + r16;
    int ilo_last = bi;                                   // block-uniform
    int n64 = __builtin_amdgcn_readfirstlane(16 - bi);   // block-uniform

    int srow = lane >> 3;         // 0..7
    int scb  = (lane & 7) ^ srow; // XOR-swizzled global colblk
    const u16* kst = kh + (size_t)(w * 16 + srow) * HD_ + scb * 8;
    const u16* vst = vh + (size_t)(w * 16 + srow) * T_ + scb * 8;
    int swz = (r16 & 7);          // reader-side swizzle

    {
        #pragma unroll
        for (int s2 = 0; s2 < 2; s2++) {
            GLL16(kst + (size_t)(s2 * 8) * HD_, &Kb[0][w * 16 + s2 * 8][0] + lane * 8);
            GLL16(vst + (size_t)(s2 * 8) * T_,  &Vb[0][w * 16 + s2 * 8][0] + lane * 8);
        }
    }
    __syncthreads();

    for (int it = 0; it < n64; ++it) {
        int kv0 = it * 64;
        int buf = it & 1;
        bool lo_on = (it <= ilo_last);
        if (it + 1 < n64) {
            int kvn = kv0 + 64;
            #pragma unroll
            for (int s2 = 0; s2 < 2; s2++) {
                GLL16(kst + (size_t)(kvn + s2 * 8) * HD_, &Kb[buf ^ 1][w * 16 + s2 * 8][0] + lane * 8);
                GLL16(vst + (size_t)(s2 * 8) * T_ + kvn,  &Vb[buf ^ 1][w * 16 + s2 * 8][0] + lane * 8);
            }
        }
        bf16x8 kf[4][2];
        #pragma unroll
        for (int n = 0; n < 4; n++)
            #pragma unroll
            for (int c = 0; c < 2; c++)
                kf[n][c] = *(const bf16x8*)&Kb[buf][n * 16 + r16][((c * 4 + quad) ^ swz) * 8];
        f32x4 sH[4] = {};
        #pragma unroll
        for (int n = 0; n < 4; n++) {
            sH[n] = MFMA(kf[n][0], qh0, sH[n], 0, 0, 0);
            sH[n] = MFMA(kf[n][1], qh1, sH[n], 0, 0, 0);
        }
        if (it == n64 - 1) {
            #pragma unroll
            for (int n = 0; n < 4; n++)
                #pragma unroll
                for (int r = 0; r < 4; r++)
                    if (kv0 + n * 16 + quad * 4 + r > qyH) sH[n][r] = -1e30f;
        }
        #pragma unroll
        for (int n = 0; n < 4; n++) {
            float p0 = __expf(sH[n][0]);
            float p1 = __expf(sH[n][1]);
            float p2 = __expf(sH[n][2]);
            float p3 = __expf(sH[n][3]);
            lH += (p0 + p1) + (p2 + p3);
            uint2 pd; pd.x = pk2bf(p0, p1); pd.y = pk2bf(p2, p3);
            *(uint2*)&P[w][1][r16][n * 16 + quad * 4] = pd;
        }
        if (lo_on) {
            f32x4 sL[4] = {};
            #pragma unroll
            for (int n = 0; n < 4; n++) {
                sL[n] = MFMA(kf[n][0], ql0, sL[n], 0, 0, 0);
                sL[n] = MFMA(kf[n][1], ql1, sL[n], 0, 0, 0);
            }
            if (it == ilo_last) {
                #pragma unroll
                for (int n = 0; n < 4; n++)
                    #pragma unroll
                    for (int r = 0; r < 4; r++)
                        if (kv0 + n * 16 + quad * 4 + r > qyL) sL[n][r] = -1e30f;
            }
            #pragma unroll
            for (int n = 0; n < 4; n++) {
                float p0 = __expf(sL[n][0]);
                float p1 = __expf(sL[n][1]);
                float p2 = __expf(sL[n][2]);
                float p3 = __expf(sL[n][3]);
                lL += (p0 + p1) + (p2 + p3);
                uint2 pd; pd.x = pk2bf(p0, p1); pd.y = pk2bf(p2, p3);
                *(uint2*)&P[w][0][r16][n * 16 + quad * 4] = pd;
            }
        }
        bf16x8 vf[4][2];
        #pragma unroll
        for (int j = 0; j < 4; j++)
            #pragma unroll
            for (int c = 0; c < 2; c++)
                vf[j][c] = *(const bf16x8*)&Vb[buf][j * 16 + r16][((c * 4 + quad) ^ swz) * 8];
        #pragma unroll
        for (int c = 0; c < 2; c++) {
            bf16x8 pfH = *(const bf16x8*)&P[w][1][r16][c * 32 + quad * 8];
            #pragma unroll
            for (int j = 0; j < 4; j++)
                oH[j] = MFMA(vf[j][c], pfH, oH[j], 0, 0, 0);
        }
        if (lo_on) {
            #pragma unroll
            for (int c = 0; c < 2; c++) {
                bf16x8 pfL = *(const bf16x8*)&P[w][0][r16][c * 32 + quad * 8];
                #pragma unroll
                for (int j = 0; j < 4; j++)
                    oL[j] = MFMA(vf[j][c], pfL, oL[j], 0, 0, 0);
            }
        }
        __syncthreads();
    }

    lH += __shfl_xor(lH, 16, 64);
    lH += __shfl_xor(lH, 32, 64);
    lL += __shfl_xor(lL, 16, 64);
    lL += __shfl_xor(lL, 32, 64);
    float invH = 1.f / lH, invL = 1.f / lL;
    int tqH = qb_hi + r16, tqL = qb_lo + r16;
    #pragma unroll
    for (int j = 0; j < 4; j++) {
        ushort4 ovH, ovL;
        ovH.x = f2bf(oH[j][0] * invH); ovH.y = f2bf(oH[j][1] * invH);
        ovH.z = f2bf(oH[j][2] * invH); ovH.w = f2bf(oH[j][3] * invH);
        ovL.x = f2bf(oL[j][0] * invL); ovL.y = f2bf(oL[j][1] * invL);
        ovL.z = f2bf(oL[j][2] * invL); ovL.w = f2bf(oL[j][3] * invL);
        *(ushort4*)(y + ((size_t)b * T_ + tqH) * C_ + h * 64 + j * 16 + quad * 4) = ovH;
        *(ushort4*)(y + ((size_t)b * T_ + tqL) * C_ + h * 64 + j * 16 + quad * 4) = ovL;
    }
}

extern "C" void kernel_launch(void* const* d_in, const int* in_sizes, int n_in,
                              void* d_out, int out_size, void* d_ws, size_t ws_size,
                              hipStream_t stream) {
    const float* x      = (const float*)d_in[0];
    const float* w_attn = (const float*)d_in[1];
    const float* b_attn = (const float*)d_in[2];
    const float* w_proj = (const float*)d_in[3];
    const float* b_proj = (const float*)d_in[4];
    float* out = (float*)d_out;

    char* ws = (char*)d_ws;
    size_t off = 0;
    auto alloc = [&](size_t bytes) {
        void* p = ws + off;
        off += (bytes + 255) & ~(size_t)255;
        return p;
    };
    const size_t M = (size_t)B_ * T_;                    // 8192
    u16* x_bf = (u16*)alloc(M * C_ * 2);                 // [8192][768]
    u16* wat  = (u16*)alloc((size_t)K3_ * C_ * 2);       // [2304][768]
    u16* wpt  = (u16*)alloc((size_t)C_ * C_ * 2);        // [768][768]
    u16* qb   = (u16*)alloc((size_t)B_ * H_ * T_ * HD_ * 2);
    u16* kb   = (u16*)alloc((size_t)B_ * H_ * T_ * HD_ * 2);
    u16* vb   = (u16*)alloc((size_t)B_ * H_ * T_ * HD_ * 2);
    u16* yb   = (u16*)alloc(M * C_ * 2);                 // [8192][768]

    prep<<<6144 + 1728 + 576, 256, 0, stream>>>(x, x_bf, w_attn, wat, w_proj, wpt);
    gemm_qkv<<<1536, 512, 0, stream>>>(x_bf, wat, b_attn, qb, kb, vb);
    attn<<<8 * 96, 256, 0, stream>>>(qb, kb, vb, yb);
    gemm_proj<<<512, 512, 0, stream>>>(yb, wpt, b_proj, out);
}

// Round 11
// 158.904 us; speedup vs baseline: 1.0378x; 1.0378x over previous
//
#include <hip/hip_runtime.h>
#include <cstdint>
#include <cstddef>

#define B_  8
#define T_  1024
#define C_  768
#define H_  12
#define HD_ 64
#define K3_ 2304   // 3*C

typedef unsigned short u16;
typedef __attribute__((ext_vector_type(8))) short bf16x8;   // 8 bf16 (4 VGPRs)
typedef __attribute__((ext_vector_type(4))) float f32x4;    // 4 fp32 acc

#define MFMA __builtin_amdgcn_mfma_f32_16x16x32_bf16

__device__ __forceinline__ u16 f2bf(float f) {
    unsigned u = __builtin_bit_cast(unsigned, f);
    u += 0x7fffu + ((u >> 16) & 1u);           // round-to-nearest-even
    return (u16)(u >> 16);
}

// pack two fp32 -> bf16x2 dword (round-half-up; P>=0, feeds bf16 MFMA)
__device__ __forceinline__ unsigned pk2bf(float a, float b) {
    unsigned ua = __builtin_bit_cast(unsigned, a) + 0x8000u;
    unsigned ub = __builtin_bit_cast(unsigned, b) + 0x8000u;
    return (ua >> 16) | (ub & 0xffff0000u);
}

// async global->LDS, 16 B per lane. LDS dest = wave-uniform base + lane*16.
#define GLL16(gp, lp) __builtin_amdgcn_global_load_lds( \
    (__attribute__((address_space(1))) unsigned int*)(gp), \
    (__attribute__((address_space(3))) unsigned int*)(lp), 16, 0, 0)

// ---------------- prep: x->bf16 + both weight transposes, one kernel ----------------
__device__ __forceinline__ void tcvt_tile(const float* __restrict__ in, u16* __restrict__ out,
                                          int R, int Cc, int bx, int by, int tid, float* tile /*32x33*/) {
    int bc = bx * 32, br = by * 32;
    int tx = tid & 31, ty = tid >> 5;   // (32, 8)
    #pragma unroll
    for (int kk = 0; kk < 32; kk += 8)
        tile[(ty + kk) * 33 + tx] = in[(size_t)(br + ty + kk) * Cc + bc + tx];
    __syncthreads();
    #pragma unroll
    for (int kk = 0; kk < 32; kk += 8)
        out[(size_t)(bc + ty + kk) * R + br + tx] = f2bf(tile[tx * 33 + ty + kk]);
}

__global__ void prep(const float* __restrict__ x, u16* __restrict__ xb,
                     const float* __restrict__ wa, u16* __restrict__ wat,
                     const float* __restrict__ wp, u16* __restrict__ wpt) {
    __shared__ float tile[32 * 33];
    int bid = blockIdx.x, tid = threadIdx.x;
    if (bid < 6144) {                      // cvt: 8192*768/4 elements of float4
        int i = bid * 256 + tid;
        float4 v = ((const float4*)x)[i];
        ushort4 o;
        o.x = f2bf(v.x); o.y = f2bf(v.y); o.z = f2bf(v.z); o.w = f2bf(v.w);
        ((ushort4*)xb)[i] = o;
    } else if (bid < 6144 + 1728) {        // w_attn [768][2304] -> [2304][768]
        int b = bid - 6144;
        tcvt_tile(wa, wat, C_, K3_, b % 72, b / 72, tid, tile);
    } else {                               // w_proj [768][768] -> [768][768]^T
        int b = bid - 7872;
        tcvt_tile(wp, wpt, C_, C_, b % 24, b / 24, tid, tile);
    }
}

// ============ high-arithmetic-intensity pipelined GEMM core ============
// 256 threads, 4 waves (2M x 2N), per-wave 64 x (NB*16) output (acc[4][NB]).
// NB=6: BM=128, BN=192, 38.4 FLOP per LDS byte (vs 19-27 in all prior configs
// which measured flat ~45us at MfmaUtil 22-24% -> LDS-read pipe carried ~2x the
// matrix pipe's per-phase load). LDS 2-slot ring = 80KB (NB=6) / 56KB (NB=3)
// -> 2 INDEPENDENT blocks/CU (one block's barrier holes filled by the other).
// Phase kt: {20 ds_read slot p=kt&1, 24*NB/3 MFMA, BAR, stage kt+2 -> slot p
// (WAR-safe behind the barrier), vmcnt(L) [L = 4+NB loads/tile: drains tile
// kt+1 ONLY, kt+2 stays in flight; never 0 in loop], BAR}. Tail: vmcnt(0).
// Ledger: enter phase with L outstanding; +L -> 2L; vmcnt(L) -> L.  Swizzle:
// 128B rows, 3-bit XOR chunk^(row&7) both sides (round-0-verified, 0 conflicts).
#define VMW0 asm volatile("s_waitcnt vmcnt(0)" ::: "memory")
#define BAR  __builtin_amdgcn_s_barrier()

template<int NB>
__device__ __forceinline__ void gemm_pipe(const u16* __restrict__ A, const u16* __restrict__ Bt,
                                          int m0, int n0, u16* SM, f32x4 (&acc)[4][NB]) {
    const int K = C_;
    const int BSLOT = NB * 2048;            // u16 per B slot (NB*32 rows * 64 u16)
    int tid = threadIdx.x;
    int lane = tid & 63, wv = tid >> 6;
    int wr = wv >> 1, wc = wv & 1;          // wave grid 2M x 2N
    int r16 = lane & 15, quad = lane >> 4;
    int sw = r16 & 7;
    int x0 = (quad ^ sw) * 8;               // kk=0 swizzled 16B chunk (u16 units)
    int x1 = ((4 + quad) ^ sw) * 8;         // kk=1
    int arow = (wr * 64 + r16) * 64;
    int brow = (wc * NB * 16 + r16) * 64;
    // staging: thread t -> row t>>3 (0..31, +32/issue), chunk (t&7)^(row&7); LDS linear
    int tr = tid >> 3;
    int tb = (tid & 7) ^ (tr & 7);
    const u16* Ag = A  + (size_t)(m0 + tr) * K + tb * 8;
    const u16* Bg = Bt + (size_t)(n0 + tr) * K + tb * 8;
    u16* SLa = SM + tid * 8;
    u16* SLb = SM + 16384 + tid * 8;
    const u16* SMB = SM + 16384;

#define STG_T(ss, kO) { \
    _Pragma("unroll") \
    for (int u_ = 0; u_ < 4; u_++) \
        GLL16(Ag + (size_t)(u_ * 32) * K + (kO), SLa + (ss) * 8192 + u_ * 2048); \
    _Pragma("unroll") \
    for (int u_ = 0; u_ < NB; u_++) \
        GLL16(Bg + (size_t)(u_ * 32) * K + (kO), SLb + (ss) * BSLOT + u_ * 2048); }
#define RDMM(rs) { \
    const u16* Ar_ = SM  + (rs) * 8192 + arow; \
    const u16* Br_ = SMB + (rs) * BSLOT + brow; \
    bf16x8 a0[4], b0[NB], a1[4], b1[NB]; \
    _Pragma("unroll") for (int i_ = 0; i_ < 4; i_++)  a0[i_] = *(const bf16x8*)&Ar_[i_ * 1024 + x0]; \
    _Pragma("unroll") for (int j_ = 0; j_ < NB; j_++) b0[j_] = *(const bf16x8*)&Br_[j_ * 1024 + x0]; \
    _Pragma("unroll") for (int i_ = 0; i_ < 4; i_++)  a1[i_] = *(const bf16x8*)&Ar_[i_ * 1024 + x1]; \
    _Pragma("unroll") for (int j_ = 0; j_ < NB; j_++) b1[j_] = *(const bf16x8*)&Br_[j_ * 1024 + x1]; \
    __builtin_amdgcn_s_setprio(1); \
    _Pragma("unroll") for (int i_ = 0; i_ < 4; i_++) \
    _Pragma("unroll") for (int j_ = 0; j_ < NB; j_++) \
        acc[i_][j_] = MFMA(a0[i_], b0[j_], acc[i_][j_], 0, 0, 0); \
    _Pragma("unroll") for (int i_ = 0; i_ < 4; i_++) \
    _Pragma("unroll") for (int j_ = 0; j_ < NB; j_++) \
        acc[i_][j_] = MFMA(a1[i_], b1[j_], acc[i_][j_], 0, 0, 0); \
    __builtin_amdgcn_s_setprio(0); }
#define VMWL { if constexpr (NB == 6) { asm volatile("s_waitcnt vmcnt(10)" ::: "memory"); } \
               else                   { asm volatile("s_waitcnt vmcnt(7)"  ::: "memory"); } }

    // prologue: tile0 -> slot0, tile1 -> slot1 (2L loads); drain tile0 (L left)
    STG_T(0, 0); STG_T(1, 64);
    VMWL; BAR;

    #pragma unroll
    for (int kt = 0; kt < 10; ++kt) {        // tiles 0..9; stages tiles 2..11
        int p = kt & 1;
        RDMM(p);
        BAR;                                 // all waves' reads of slot p done
        STG_T(p, (kt + 2) * 64);             // overwrite slot p with tile kt+2
        VMWL;                                // tile kt+1 fully landed
        BAR;
    }
    {                                        // kt=10 (slot 0, tile 10)
        RDMM(0);
        VMW0; BAR;                           // tile 11 fully landed
    }
    {                                        // kt=11 (slot 1, tile 11)
        RDMM(1);
    }
#undef STG_T
#undef RDMM
#undef VMWL
}

// ---------------- GEMM1: qkv = x @ w_attn + b_attn, scatter to q/k/v ----------------
// 768 blocks at 2 blocks/CU; 12 n-panels of 192 cols.
__launch_bounds__(256, 2)
__global__ void gemm_qkv(const u16* __restrict__ A, const u16* __restrict__ Bt,
                         const float* __restrict__ bias,
                         u16* __restrict__ q, u16* __restrict__ k, u16* __restrict__ v) {
    __shared__ __align__(16) u16 SM[40960];      // 80KB ring; Cs overlays in epilogue
    int id = blockIdx.x;                          // 768 = 8 xcd * (8 m x 12 n)
    int xcd = id & 7, j = id >> 3;
    int m0 = (xcd * 8 + (j & 7)) * 128;           // XCD owns contiguous 8-tile A slab
    int np = j >> 3;                              // n-panel 0..11 (192 cols each)
    f32x4 acc[4][6] = {};
    gemm_pipe<6>(A, Bt, m0, np * 192, SM, acc);

    int tid = threadIdx.x;
    int lane = tid & 63, wv = tid >> 6;
    int wr = wv >> 1, wc = wv & 1;
    int r16 = lane & 15, quad = lane >> 4;
    __syncthreads();                              // ring reads drained before Cs overlay

    int sec = np >> 2;                 // block-uniform: 0=q, 1=k, 2=v (4 panels each)
    int cc0 = (np & 3) * 192;          // col offset within section (3 heads/panel)
    int b = m0 >> 10, t0 = m0 & 1023;

    if (sec == 2) {
        #pragma unroll
        for (int i = 0; i < 4; i++) {
            #pragma unroll
            for (int jj = 0; jj < 6; jj++) {
                int cc = cc0 + wc * 96 + jj * 16 + r16;
                float bv = bias[2 * C_ + cc];
                int h = cc >> 6, hd = cc & 63;
                int t = t0 + wr * 64 + i * 16 + quad * 4;
                ushort4 ov;
                ov.x = f2bf(acc[i][jj][0] + bv); ov.y = f2bf(acc[i][jj][1] + bv);
                ov.z = f2bf(acc[i][jj][2] + bv); ov.w = f2bf(acc[i][jj][3] + bv);
                *(ushort4*)(v + (((size_t)b * H_ + h) * HD_ + hd) * T_ + t) = ov;
            }
        }
    } else {
        float scale = (sec == 0) ? 0.125f : 1.0f;
        u16* dst = (sec == 0) ? q : k;
        u16 (*Cs)[200] = (u16(*)[200])SM;          // 128x200 (400B rows, 16B-aligned)
        #pragma unroll
        for (int i = 0; i < 4; i++)
            #pragma unroll
            for (int jj = 0; jj < 6; jj++) {
                int col = wc * 96 + jj * 16 + r16;
                float bv = bias[sec * C_ + cc0 + col];
                #pragma unroll
                for (int r = 0; r < 4; r++)
                    Cs[wr * 64 + i * 16 + quad * 4 + r][col] = f2bf((acc[i][jj][r] + bv) * scale);
            }
        __syncthreads();
        if (tid < 192) {                           // 8 rows x 24 chunks of 16B per pass
            int ch = tid % 24;                     // 16B chunk within 192 cols
            int rs = tid / 24;                     // 0..7
            int cc = cc0 + ch * 8;
            int h = cc >> 6, hd = cc & 63;         // 8-col chunk never crosses a head
            u16* dbase = dst + ((size_t)b * H_ + h) * T_ * HD_ + hd;
            #pragma unroll
            for (int p = 0; p < 16; p++) {
                int rl = p * 8 + rs;
                *(uint4*)(dbase + (size_t)(t0 + rl) * HD_) = *(const uint4*)&Cs[rl][ch * 8];
            }
        }
    }
}

// ---------------- GEMM2: out = y @ w_proj + b_proj (fp32 out) ----------------
// 512 blocks = exactly one 2-blocks/CU round; 8 n-panels of 96 cols.
__launch_bounds__(256, 2)
__global__ void gemm_proj(const u16* __restrict__ A, const u16* __restrict__ Bt,
                          const float* __restrict__ bias, float* __restrict__ out) {
    __shared__ __align__(16) u16 SM[28672];       // 56KB ring
    int id = blockIdx.x;                          // 512 = 8 xcd * (8 m x 8 n)
    int xcd = id & 7, j = id >> 3;
    int m0 = (xcd * 8 + (j & 7)) * 128;
    int n0 = (j >> 3) * 96;
    f32x4 acc[4][3] = {};
    gemm_pipe<3>(A, Bt, m0, n0, SM, acc);

    int tid = threadIdx.x;
    int lane = tid & 63, wv = tid >> 6;
    int wr = wv >> 1, wc = wv & 1;
    int r16 = lane & 15, quad = lane >> 4;
    #pragma unroll
    for (int i = 0; i < 4; i++) {
        #pragma unroll
        for (int jj = 0; jj < 3; jj++) {
            int gn = n0 + wc * 48 + jj * 16 + r16;
            float bv = bias[gn];
            #pragma unroll
            for (int r = 0; r < 4; r++) {
                int gm = m0 + wr * 64 + i * 16 + quad * 4 + r;
                out[(size_t)gm * C_ + gn] = acc[i][jj][r] + bv;
            }
        }
    }
}

// ---------------- Flash attention: LDS-staged K/V (double-buffered), paired q-tiles ----
__launch_bounds__(256, 2)
__global__ void attn(const u16* __restrict__ q, const u16* __restrict__ k,
                     const u16* __restrict__ v, u16* __restrict__ y) {
    __shared__ __align__(16) u16 Kb[2][64][64];     // [buf][key][hd]
    __shared__ __align__(16) u16 Vb[2][64][64];     // [buf][hd][key]
    __shared__ __align__(16) u16 P[4][2][16][72];   // per-wave, per-tile P^T
    int tid = threadIdx.x, lane = tid & 63, w = tid >> 6;
    int r16 = lane & 15, quad = lane >> 4;
    int id = blockIdx.x;
    int bh = id % 96;             // same head -> ids 96 apart -> same XCD (96%8==0)
    int bi = id / 96;             // 0..7; bi=0 (longest, n64=16) dispatched first
    int b = bh / H_, h = bh - b * H_;
    int x = bi * 4 + w;           // 0..31
    int t_lo = x, t_hi = 63 - x;
    int qb_lo = t_lo * 16, qb_hi = t_hi * 16;
    const u16* qh = q + (size_t)bh * T_ * HD_;
    const u16* kh = k + (size_t)bh * T_ * HD_;
    const u16* vh = v + (size_t)bh * HD_ * T_;   // [HD][T]

    bf16x8 ql0 = *(const bf16x8*)(qh + (size_t)(qb_lo + r16) * HD_ + quad * 8);
    bf16x8 ql1 = *(const bf16x8*)(qh + (size_t)(qb_lo + r16) * HD_ + 32 + quad * 8);
    bf16x8 qh0 = *(const bf16x8*)(qh + (size_t)(qb_hi + r16) * HD_ + quad * 8);
    bf16x8 qh1 = *(const bf16x8*)(qh + (size_t)(qb_hi + r16) * HD_ + 32 + quad * 8);

    f32x4 oL[4] = {}, oH[4] = {};
    float lL = 0.f, lH = 0.f;
    int qyL = qb_lo + r16, qyH = qb_hi + r16;
    int ilo_last = bi;                                   // block-uniform
    int n64 = __builtin_amdgcn_readfirstlane(16 - bi);   // block-uniform

    int srow = lane >> 3;         // 0..7
    int scb  = (lane & 7) ^ srow; // XOR-swizzled global colblk
    const u16* kst = kh + (size_t)(w * 16 + srow) * HD_ + scb * 8;
    const u16* vst = vh + (size_t)(w * 16 + srow) * T_ + scb * 8;
    int swz = (r16 & 7);          // reader-side swizzle

    {
        #pragma unroll
        for (int s2 = 0; s2 < 2; s2++) {
            GLL16(kst + (size_t)(s2 * 8) * HD_, &Kb[0][w * 16 + s2 * 8][0] + lane * 8);
            GLL16(vst + (size_t)(s2 * 8) * T_,  &Vb[0][w * 16 + s2 * 8][0] + lane * 8);
        }
    }
    __syncthreads();

    for (int it = 0; it < n64; ++it) {
        int kv0 = it * 64;
        int buf = it & 1;
        bool lo_on = (it <= ilo_last);
        if (it + 1 < n64) {
            int kvn = kv0 + 64;
            #pragma unroll
            for (int s2 = 0; s2 < 2; s2++) {
                GLL16(kst + (size_t)(kvn + s2 * 8) * HD_, &Kb[buf ^ 1][w * 16 + s2 * 8][0] + lane * 8);
                GLL16(vst + (size_t)(s2 * 8) * T_ + kvn,  &Vb[buf ^ 1][w * 16 + s2 * 8][0] + lane * 8);
            }
        }
        bf16x8 kf[4][2];
        #pragma unroll
        for (int n = 0; n < 4; n++)
            #pragma unroll
            for (int c = 0; c < 2; c++)
                kf[n][c] = *(const bf16x8*)&Kb[buf][n * 16 + r16][((c * 4 + quad) ^ swz) * 8];
        f32x4 sH[4] = {};
        #pragma unroll
        for (int n = 0; n < 4; n++) {
            sH[n] = MFMA(kf[n][0], qh0, sH[n], 0, 0, 0);
            sH[n] = MFMA(kf[n][1], qh1, sH[n], 0, 0, 0);
        }
        if (it == n64 - 1) {
            #pragma unroll
            for (int n = 0; n < 4; n++)
                #pragma unroll
                for (int r = 0; r < 4; r++)
                    if (kv0 + n * 16 + quad * 4 + r > qyH) sH[n][r] = -1e30f;
        }
        #pragma unroll
        for (int n = 0; n < 4; n++) {
            float p0 = __expf(sH[n][0]);
            float p1 = __expf(sH[n][1]);
            float p2 = __expf(sH[n][2]);
            float p3 = __expf(sH[n][3]);
            lH += (p0 + p1) + (p2 + p3);
            uint2 pd; pd.x = pk2bf(p0, p1); pd.y = pk2bf(p2, p3);
            *(uint2*)&P[w][1][r16][n * 16 + quad * 4] = pd;
        }
        if (lo_on) {
            f32x4 sL[4] = {};
            #pragma unroll
            for (int n = 0; n < 4; n++) {
                sL[n] = MFMA(kf[n][0], ql0, sL[n], 0, 0, 0);
                sL[n] = MFMA(kf[n][1], ql1, sL[n], 0, 0, 0);
            }
            if (it == ilo_last) {
                #pragma unroll
                for (int n = 0; n < 4; n++)
                    #pragma unroll
                    for (int r = 0; r < 4; r++)
                        if (kv0 + n * 16 + quad * 4 + r > qyL) sL[n][r] = -1e30f;
            }
            #pragma unroll
            for (int n = 0; n < 4; n++) {
                float p0 = __expf(sL[n][0]);
                float p1 = __expf(sL[n][1]);
                float p2 = __expf(sL[n][2]);
                float p3 = __expf(sL[n][3]);
                lL += (p0 + p1) + (p2 + p3);
                uint2 pd; pd.x = pk2bf(p0, p1); pd.y = pk2bf(p2, p3);
                *(uint2*)&P[w][0][r16][n * 16 + quad * 4] = pd;
            }
        }
        bf16x8 vf[4][2];
        #pragma unroll
        for (int j = 0; j < 4; j++)
            #pragma unroll
            for (int c = 0; c < 2; c++)
                vf[j][c] = *(const bf16x8*)&Vb[buf][j * 16 + r16][((c * 4 + quad) ^ swz) * 8];
        #pragma unroll
        for (int c = 0; c < 2; c++) {
            bf16x8 pfH = *(const bf16x8*)&P[w][1][r16][c * 32 + quad * 8];
            #pragma unroll
            for (int j = 0; j < 4; j++)
                oH[j] = MFMA(vf[j][c], pfH, oH[j], 0, 0, 0);
        }
        if (lo_on) {
            #pragma unroll
            for (int c = 0; c < 2; c++) {
                bf16x8 pfL = *(const bf16x8*)&P[w][0][r16][c * 32 + quad * 8];
                #pragma unroll
                for (int j = 0; j < 4; j++)
                    oL[j] = MFMA(vf[j][c], pfL, oL[j], 0, 0, 0);
            }
        }
        __syncthreads();
    }

    lH += __shfl_xor(lH, 16, 64);
    lH += __shfl_xor(lH, 32, 64);
    lL += __shfl_xor(lL, 16, 64);
    lL += __shfl_xor(lL, 32, 64);
    float invH = 1.f / lH, invL = 1.f / lL;
    int tqH = qb_hi + r16, tqL = qb_lo + r16;
    #pragma unroll
    for (int j = 0; j < 4; j++) {
        ushort4 ovH, ovL;
        ovH.x = f2bf(oH[j][0] * invH); ovH.y = f2bf(oH[j][1] * invH);
        ovH.z = f2bf(oH[j][2] * invH); ovH.w = f2bf(oH[j][3] * invH);
        ovL.x = f2bf(oL[j][0] * invL); ovL.y = f2bf(oL[j][1] * invL);
        ovL.z = f2bf(oL[j][2] * invL); ovL.w = f2bf(oL[j][3] * invL);
        *(ushort4*)(y + ((size_t)b * T_ + tqH) * C_ + h * 64 + j * 16 + quad * 4) = ovH;
        *(ushort4*)(y + ((size_t)b * T_ + tqL) * C_ + h * 64 + j * 16 + quad * 4) = ovL;
    }
}

extern "C" void kernel_launch(void* const* d_in, const int* in_sizes, int n_in,
                              void* d_out, int out_size, void* d_ws, size_t ws_size,
                              hipStream_t stream) {
    const float* x      = (const float*)d_in[0];
    const float* w_attn = (const float*)d_in[1];
    const float* b_attn = (const float*)d_in[2];
    const float* w_proj = (const float*)d_in[3];
    const float* b_proj = (const float*)d_in[4];
    float* out = (float*)d_out;

    char* ws = (char*)d_ws;
    size_t off = 0;
    auto alloc = [&](size_t bytes) {
        void* p = ws + off;
        off += (bytes + 255) & ~(size_t)255;
        return p;
    };
    const size_t M = (size_t)B_ * T_;                    // 8192
    u16* x_bf = (u16*)alloc(M * C_ * 2);                 // [8192][768]
    u16* wat  = (u16*)alloc((size_t)K3_ * C_ * 2);       // [2304][768]
    u16* wpt  = (u16*)alloc((size_t)C_ * C_ * 2);        // [768][768]
    u16* qb   = (u16*)alloc((size_t)B_ * H_ * T_ * HD_ * 2);
    u16* kb   = (u16*)alloc((size_t)B_ * H_ * T_ * HD_ * 2);
    u16* vb   = (u16*)alloc((size_t)B_ * H_ * T_ * HD_ * 2);
    u16* yb   = (u16*)alloc(M * C_ * 2);                 // [8192][768]

    prep<<<6144 + 1728 + 576, 256, 0, stream>>>(x, x_bf, w_attn, wat, w_proj, wpt);
    gemm_qkv<<<768, 256, 0, stream>>>(x_bf, wat, b_attn, qb, kb, vb);
    attn<<<8 * 96, 256, 0, stream>>>(qb, kb, vb, yb);
    gemm_proj<<<512, 256, 0, stream>>>(yb, wpt, b_proj, out);
}